// Round 17
// baseline (127.633 us; speedup 1.0000x reference)
//
#include <hip/hip_runtime.h>
#include <hip/hip_bf16.h>

typedef unsigned short u16;
typedef unsigned int u32;

typedef float f32x4 __attribute__((ext_vector_type(4)));
typedef short bf16x8 __attribute__((ext_vector_type(8)));

#define HDIM 64
#define EPS 1e-5f
#define XROW 68      // u16 stride per LDS row (8B-aligned, bank-spread)

// ---------- helpers ----------

__device__ __forceinline__ float wave_sum64(float v) {
    v += __shfl_xor(v, 1, 64);
    v += __shfl_xor(v, 2, 64);
    v += __shfl_xor(v, 4, 64);
    v += __shfl_xor(v, 8, 64);
    v += __shfl_xor(v, 16, 64);
    v += __shfl_xor(v, 32, 64);
    return v;
}

__device__ __forceinline__ float bcast(float v, int k) {
    return __int_as_float(__builtin_amdgcn_readlane(__float_as_int(v), k));
}

// round-to-nearest-even f32 -> bf16 bits
__device__ __forceinline__ u16 f2bf(float f) {
    u32 u = __float_as_uint(f);
    u32 r = (u + 0x7fffu + ((u >> 16) & 1u)) >> 16;
    return (u16)r;
}

__device__ __forceinline__ u32 pack2(float e0, float e1) {
    return (u32)f2bf(e0) | ((u32)f2bf(e1) << 16);
}
__device__ __forceinline__ float bflo(u32 w) { return __uint_as_float(w << 16); }
__device__ __forceinline__ float bfhi(u32 w) { return __uint_as_float(w & 0xffff0000u); }

// ---------- prep: bf16 weight copies (bil_w transposed, natural) ----------
__global__ __launch_bounds__(256) void prep_kernel(
    const float* __restrict__ lin1_w, const float* __restrict__ lin2_w,
    const float* __restrict__ bil_w,
    u16* __restrict__ w1bf, u16* __restrict__ w2bf, u16* __restrict__ btbf)
{
    const int gtid = blockIdx.x * 256 + threadIdx.x;
    for (int i = gtid; i < 4096; i += gridDim.x * 256) {
        w1bf[i] = f2bf(lin1_w[i]);            // row-major [h][k]
        w2bf[i] = f2bf(lin2_w[i]);
        const int g = i >> 6, h = i & 63;
        btbf[i] = f2bf(bil_w[h * 64 + g]);    // btbf[g][h] = bil_w[h][g]
    }
}

// ---------- MFMA fragment loaders (validated r8 mappings) ----------
// A (M=16 x K=32), tile m: lane l holds row 16m + l%16, k = 8*(l>>4)+i (+32s)
__device__ __forceinline__ bf16x8 load_afrag(const u16* Xs, int l, int m, int s) {
    const int row = 16 * m + (l & 15);
    const int k0  = 8 * (l >> 4) + 32 * s;
    union { uint2 u[2]; bf16x8 f; } c;
    c.u[0] = *(const uint2*)&Xs[row * XROW + k0];
    c.u[1] = *(const uint2*)&Xs[row * XROW + k0 + 4];
    return c.f;
}

// B (K=32 x N=16): lane l holds col l%16 (+16t), k = 8*(l>>4)+32s.
__device__ __forceinline__ bf16x8 load_bfrag(const u16* __restrict__ W,
                                             int l, int t, int s) {
    const int n  = (l & 15) + 16 * t;
    const int k0 = 8 * (l >> 4) + 32 * s;
    return *(const bf16x8*)&W[n * 64 + k0];
}

// relu(acc + bias) then LN across h (4 tiles x 4 regs, 16-lane reduce).
// C/D layout: col = l&15 (+16t), row(node) = (l>>4)*4 + reg
__device__ __forceinline__ void relu_ln_acc(f32x4* acc, const float* biasv,
                                            const float* gv, const float* bvv) {
    float s[4] = {0.f,0.f,0.f,0.f}, q[4] = {0.f,0.f,0.f,0.f};
#pragma unroll
    for (int t = 0; t < 4; ++t)
#pragma unroll
        for (int j = 0; j < 4; ++j) {
            float v = fmaxf(acc[t][j] + biasv[t], 0.f);
            acc[t][j] = v;
            s[j] += v; q[j] = fmaf(v, v, q[j]);
        }
#pragma unroll
    for (int j = 0; j < 4; ++j) {
#pragma unroll
        for (int m = 1; m < 16; m <<= 1) {
            s[j] += __shfl_xor(s[j], m, 64);
            q[j] += __shfl_xor(q[j], m, 64);
        }
        const float mu = s[j] * 0.015625f;
        const float rs = rsqrtf(q[j] * 0.015625f - mu * mu + EPS);
#pragma unroll
        for (int t = 0; t < 4; ++t)
            acc[t][j] = (acc[t][j] - mu) * rs * gv[t] + bvv[t];
    }
}

// scatter acc (bf16) into LDS rows [16m + node][h]  (natural layout)
__device__ __forceinline__ void acc_to_lds(u16* Xs, const f32x4* acc, int l, int m) {
    const int hcol = l & 15;
#pragma unroll
    for (int j = 0; j < 4; ++j) {
        const int row = 16 * m + (l >> 4) * 4 + j;
#pragma unroll
        for (int t = 0; t < 4; ++t)
            Xs[row * XROW + hcol + 16 * t] = f2bf(acc[t][j]);
    }
}

// coalesced copy of 32 LDS rows (64 bf16 each) to global table; 2 lanes/row
__device__ __forceinline__ void lds_to_global32(u16* __restrict__ T, const u16* Xs,
                                                int l, int n0, int nnodes) {
    const int row  = l >> 1;
    const int node = n0 + row;
    if (node >= nnodes) return;
    const int c0 = (l & 1) * 32;
    const u16* src = &Xs[row * XROW + c0];
    uint2 p[8];
#pragma unroll
    for (int j = 0; j < 8; ++j) p[j] = *(const uint2*)&src[4*j];
    uint4* d = (uint4*)(T + (size_t)node * HDIM + c0);
    d[0] = make_uint4(p[0].x, p[0].y, p[1].x, p[1].y);
    d[1] = make_uint4(p[2].x, p[2].y, p[3].x, p[3].y);
    d[2] = make_uint4(p[4].x, p[4].y, p[5].x, p[5].y);
    d[3] = make_uint4(p[6].x, p[6].y, p[7].x, p[7].y);
}

// ---------- phase 1: MFMA per-node transform -> bf16 tables ----------
// One wave per 32 nodes; direct z->fragment loads (no input-staging LDS).
// __syncthreads() at every cross-lane LDS transition: correctness must not
// depend on same-wave LDS ordering surviving compiler reordering (r15/r16).
__global__ __launch_bounds__(256) void phase1_kernel(
    const float* __restrict__ z,
    const float* __restrict__ root_w, const float* __restrict__ root_b,
    const u16* __restrict__ w1bf, const float* __restrict__ lin1_b,
    const u16* __restrict__ w2bf, const float* __restrict__ lin2_b,
    const u16* __restrict__ btbf,
    const float* __restrict__ norm_g, const float* __restrict__ norm_b,
    u16* __restrict__ T1, u16* __restrict__ T2, int nnodes)
{
    __shared__ u16 XsAll[4][32 * XROW];      // 17.4 KB/block (bounce buffer)

    const int tid = threadIdx.x;
    const int wid = tid >> 6;
    const int l   = tid & 63;
    u16* Xs = XsAll[wid];

    const int n0 = (blockIdx.x * 4 + wid) * 32;

    const int arow = l & 15;
    const int kg   = (l >> 4) * 8;           // this lane's k-base (s=0)

    // per-lane norm params for its own k slices (shared across m tiles)
    float4 gk0 = *(const float4*)&norm_g[kg];
    float4 gk1 = *(const float4*)&norm_g[kg + 4];
    float4 gk2 = *(const float4*)&norm_g[kg + 32];
    float4 gk3 = *(const float4*)&norm_g[kg + 36];
    float4 bk0 = *(const float4*)&norm_b[kg];
    float4 bk1 = *(const float4*)&norm_b[kg + 4];
    float4 bk2 = *(const float4*)&norm_b[kg + 32];
    float4 bk3 = *(const float4*)&norm_b[kg + 36];

    // ---- direct z -> LN -> A fragments (registers only) ----
    bf16x8 a[2][2];
#pragma unroll
    for (int m = 0; m < 2; ++m) {
        const int node = n0 + 16 * m + arow;
        float r[16];
        if (node == 0) {
#pragma unroll
            for (int q = 0; q < 2; ++q) {
                const float4 aw = *(const float4*)&root_w[kg + 4*q];
                const float4 ab = *(const float4*)&root_b[kg + 4*q];
                r[4*q]   = aw.x + ab.x; r[4*q+1] = aw.y + ab.y;
                r[4*q+2] = aw.z + ab.z; r[4*q+3] = aw.w + ab.w;
                const float4 cw = *(const float4*)&root_w[kg + 32 + 4*q];
                const float4 cb = *(const float4*)&root_b[kg + 32 + 4*q];
                r[8+4*q]   = cw.x + cb.x; r[8+4*q+1] = cw.y + cb.y;
                r[8+4*q+2] = cw.z + cb.z; r[8+4*q+3] = cw.w + cb.w;
            }
        } else if (node < nnodes) {
            const float* zp = z + (size_t)(node - 1) * HDIM + kg;
            const float4 v0 = *(const float4*)(zp);
            const float4 v1 = *(const float4*)(zp + 4);
            const float4 v2 = *(const float4*)(zp + 32);
            const float4 v3 = *(const float4*)(zp + 36);
            r[0]=v0.x; r[1]=v0.y; r[2]=v0.z; r[3]=v0.w;
            r[4]=v1.x; r[5]=v1.y; r[6]=v1.z; r[7]=v1.w;
            r[8]=v2.x; r[9]=v2.y; r[10]=v2.z; r[11]=v2.w;
            r[12]=v3.x; r[13]=v3.y; r[14]=v3.z; r[15]=v3.w;
        } else {
#pragma unroll
            for (int k = 0; k < 16; ++k) r[k] = 0.f;
        }
        // row stats: 4 lanes (arow, +16, +32, +48) hold the 64 elements
        float s = 0.f, sq = 0.f;
#pragma unroll
        for (int k = 0; k < 16; ++k) { s += r[k]; sq = fmaf(r[k], r[k], sq); }
        s += __shfl_xor(s, 16, 64);  sq += __shfl_xor(sq, 16, 64);
        s += __shfl_xor(s, 32, 64);  sq += __shfl_xor(sq, 32, 64);
        const float mu = s * 0.015625f;
        const float rs = rsqrtf(sq * 0.015625f - mu * mu + EPS);

        const float gA[8] = {gk0.x,gk0.y,gk0.z,gk0.w, gk1.x,gk1.y,gk1.z,gk1.w};
        const float bA[8] = {bk0.x,bk0.y,bk0.z,bk0.w, bk1.x,bk1.y,bk1.z,bk1.w};
        const float gB[8] = {gk2.x,gk2.y,gk2.z,gk2.w, gk3.x,gk3.y,gk3.z,gk3.w};
        const float bB[8] = {bk2.x,bk2.y,bk2.z,bk2.w, bk3.x,bk3.y,bk3.z,bk3.w};
        union { u32 u[4]; bf16x8 f; } c0, c1;
#pragma unroll
        for (int j = 0; j < 4; ++j) {
            c0.u[j] = pack2((r[2*j]   - mu) * rs * gA[2*j]   + bA[2*j],
                            (r[2*j+1] - mu) * rs * gA[2*j+1] + bA[2*j+1]);
            c1.u[j] = pack2((r[8+2*j]   - mu) * rs * gB[2*j]   + bB[2*j],
                            (r[8+2*j+1] - mu) * rs * gB[2*j+1] + bB[2*j+1]);
        }
        a[m][0] = c0.f;
        a[m][1] = c1.f;
    }

    // ---- per-lane output-column constants ----
    const int hcol = l & 15;
    float gv[4], bv[4], b1v[4], b2v[4];
#pragma unroll
    for (int t = 0; t < 4; ++t) {
        gv[t]  = norm_g[hcol + 16*t];
        bv[t]  = norm_b[hcol + 16*t];
        b1v[t] = lin1_b[hcol + 16*t];
        b2v[t] = lin2_b[hcol + 16*t];
    }

    // ---- y2 = zz@W2^T, y1 = zz@W1^T (B frags shared across tiles) ----
    f32x4 acc2[2][4], acc1[2][4];
#pragma unroll
    for (int t = 0; t < 4; ++t) {
        const bf16x8 b0 = load_bfrag(w2bf, l, t, 0);
        const bf16x8 b1 = load_bfrag(w2bf, l, t, 1);
#pragma unroll
        for (int m = 0; m < 2; ++m) {
            f32x4 c = {0.f, 0.f, 0.f, 0.f};
            c = __builtin_amdgcn_mfma_f32_16x16x32_bf16(a[m][0], b0, c, 0, 0, 0);
            c = __builtin_amdgcn_mfma_f32_16x16x32_bf16(a[m][1], b1, c, 0, 0, 0);
            acc2[m][t] = c;
        }
    }
#pragma unroll
    for (int t = 0; t < 4; ++t) {
        const bf16x8 b0 = load_bfrag(w1bf, l, t, 0);
        const bf16x8 b1 = load_bfrag(w1bf, l, t, 1);
#pragma unroll
        for (int m = 0; m < 2; ++m) {
            f32x4 c = {0.f, 0.f, 0.f, 0.f};
            c = __builtin_amdgcn_mfma_f32_16x16x32_bf16(a[m][0], b0, c, 0, 0, 0);
            c = __builtin_amdgcn_mfma_f32_16x16x32_bf16(a[m][1], b1, c, 0, 0, 0);
            acc1[m][t] = c;
        }
    }

    // ---- x2 -> Xs -> T2 ----
    relu_ln_acc(acc2[0], b2v, gv, bv);
    relu_ln_acc(acc2[1], b2v, gv, bv);
    acc_to_lds(Xs, acc2[0], l, 0);
    acc_to_lds(Xs, acc2[1], l, 1);
    __syncthreads();                         // RAW: writes visible to all lanes
    lds_to_global32(T2, Xs, l, n0, nnodes);
    __syncthreads();                         // WAR: reads done before overwrite

    // ---- x1 -> Xs ----
    relu_ln_acc(acc1[0], b1v, gv, bv);
    relu_ln_acc(acc1[1], b1v, gv, bv);
    acc_to_lds(Xs, acc1[0], l, 0);
    acc_to_lds(Xs, acc1[1], l, 1);
    __syncthreads();                         // RAW
#pragma unroll
    for (int m = 0; m < 2; ++m) {
        a[m][0] = load_afrag(Xs, l, m, 0);
        a[m][1] = load_afrag(Xs, l, m, 1);
    }
    __syncthreads();                         // WAR

    // ---- t = x1 @ bil_w -> T1 (no bias/relu/LN) ----
    f32x4 acc3[2][4];
#pragma unroll
    for (int t = 0; t < 4; ++t) {
        const bf16x8 b0 = load_bfrag(btbf, l, t, 0);
        const bf16x8 b1 = load_bfrag(btbf, l, t, 1);
#pragma unroll
        for (int m = 0; m < 2; ++m) {
            f32x4 c = {0.f, 0.f, 0.f, 0.f};
            c = __builtin_amdgcn_mfma_f32_16x16x32_bf16(a[m][0], b0, c, 0, 0, 0);
            c = __builtin_amdgcn_mfma_f32_16x16x32_bf16(a[m][1], b1, c, 0, 0, 0);
            acc3[m][t] = c;
        }
    }
    acc_to_lds(Xs, acc3[0], l, 0);
    acc_to_lds(Xs, acc3[1], l, 1);
    __syncthreads();                         // RAW
    lds_to_global32(T1, Xs, l, n0, nnodes);
}

// ---------- phase 2: per-edge gather + 64-dot (r8 verbatim) ----------
__global__ __launch_bounds__(256) void phase2_kernel(
    const int* __restrict__ arcs,
    const u16* __restrict__ T1, const u16* __restrict__ T2,
    const float* __restrict__ bil_b,
    float* __restrict__ out, int E)
{
    const int tid = blockIdx.x * 256 + threadIdx.x;
    const int e = tid >> 3;
    if (e >= E) return;
    const int l8 = tid & 7;

    const int i0 = arcs[2 * e];
    const int i1 = arcs[2 * e + 1];

    const uint4* p1 = (const uint4*)(T1 + (size_t)i0 * HDIM) + l8;
    const uint4* p2 = (const uint4*)(T2 + (size_t)i1 * HDIM) + l8;
    uint4 u = *p1;
    uint4 v = *p2;

    float s = 0.f;
    {
        u32 ua[4] = {u.x, u.y, u.z, u.w};
        u32 va[4] = {v.x, v.y, v.z, v.w};
#pragma unroll
        for (int i = 0; i < 4; ++i) {
            s = fmaf(bflo(ua[i]), bflo(va[i]), s);
            s = fmaf(bfhi(ua[i]), bfhi(va[i]), s);
        }
    }
    s += __shfl_xor(s, 1, 64);
    s += __shfl_xor(s, 2, 64);
    s += __shfl_xor(s, 4, 64);
    if (l8 == 0) out[e] = s + bil_b[0];
}

// ---------- fallback: per-edge full recompute (if ws too small) ----------
__device__ __forceinline__ float lnorm_w(float v, float g, float b) {
    float mu = wave_sum64(v) * 0.015625f;
    float d  = v - mu;
    float var = wave_sum64(d * d) * 0.015625f;
    return d * rsqrtf(var + EPS) * g + b;
}

__global__ __launch_bounds__(256) void edge_direct_kernel(
    const float* __restrict__ z, const int* __restrict__ arcs,
    const float* __restrict__ root_w, const float* __restrict__ root_b,
    const float* __restrict__ lin1_w, const float* __restrict__ lin1_b,
    const float* __restrict__ lin2_w, const float* __restrict__ lin2_b,
    const float* __restrict__ bil_w, const float* __restrict__ bil_b,
    const float* __restrict__ norm_g, const float* __restrict__ norm_b,
    float* __restrict__ out, int E, int nnodes)
{
    __shared__ float W1t[4096], W2t[4096], Bs[4096];
    const int tid = threadIdx.x;
    for (int i = tid; i < 4096; i += 256) {
        int h = i >> 6, k = i & 63;
        W1t[(k << 6) | h] = lin1_w[i];
        W2t[(k << 6) | h] = lin2_w[i];
        Bs[i] = bil_w[i];
    }
    __syncthreads();

    const int lane = tid & 63;
    const float g  = norm_g[lane], bt = norm_b[lane];
    const float b1 = lin1_b[lane], b2 = lin2_b[lane];
    const float rootv = root_w[lane] + root_b[lane];

    const int gwave = (blockIdx.x * 256 + tid) >> 6;
    const int nwaves = (gridDim.x * 256) >> 6;

    for (int e = gwave; e < E; e += nwaves) {
        int i0 = arcs[2 * e], i1 = arcs[2 * e + 1];
        float v0 = (i0 == 0) ? rootv : z[(size_t)(i0 - 1) * HDIM + lane];
        float v1 = (i1 == 0) ? rootv : z[(size_t)(i1 - 1) * HDIM + lane];
        float l0 = lnorm_w(v0, g, bt);
        float l1 = lnorm_w(v1, g, bt);
        float a1 = 0.f, a2 = 0.f;
#pragma unroll
        for (int k = 0; k < 64; ++k) {
            a1 = fmaf(bcast(l0, k), W1t[(k << 6) | lane], a1);
            a2 = fmaf(bcast(l1, k), W2t[(k << 6) | lane], a2);
        }
        float x1 = lnorm_w(fmaxf(a1 + b1, 0.f), g, bt);
        float x2 = lnorm_w(fmaxf(a2 + b2, 0.f), g, bt);
        float w1 = 0.f;
#pragma unroll
        for (int h = 0; h < 64; ++h)
            w1 = fmaf(bcast(x1, h), Bs[(h << 6) | lane], w1);
        float sc = wave_sum64(w1 * x2);
        if (lane == 0) out[e] = sc + bil_b[0];
    }
}

// ---------- launch ----------
extern "C" void kernel_launch(void* const* d_in, const int* in_sizes, int n_in,
                              void* d_out, int out_size, void* d_ws, size_t ws_size,
                              hipStream_t stream) {
    const float* z      = (const float*)d_in[0];
    const int*   arcs   = (const int*)  d_in[1];
    const float* root_w = (const float*)d_in[2];
    const float* root_b = (const float*)d_in[3];
    const float* lin1_w = (const float*)d_in[4];
    const float* lin1_b = (const float*)d_in[5];
    const float* lin2_w = (const float*)d_in[6];
    const float* lin2_b = (const float*)d_in[7];
    const float* bil_w  = (const float*)d_in[8];
    const float* bil_b  = (const float*)d_in[9];
    const float* norm_g = (const float*)d_in[10];
    const float* norm_b = (const float*)d_in[11];
    float* out = (float*)d_out;

    const int E      = in_sizes[1] / 2;
    const int nnodes = in_sizes[0] / HDIM + 1;

    const size_t tbl  = (size_t)nnodes * HDIM * sizeof(u16);
    const size_t need = 2 * tbl + 3 * 4096 * sizeof(u16);

    if (ws_size >= need) {
        u16* T1   = (u16*)d_ws;
        u16* T2   = (u16*)((char*)d_ws + tbl);
        u16* w1bf = (u16*)((char*)d_ws + 2 * tbl);
        u16* w2bf = w1bf + 4096;
        u16* btbf = w2bf + 4096;

        prep_kernel<<<16, 256, 0, stream>>>(lin1_w, lin2_w, bil_w, w1bf, w2bf, btbf);

        const int blocks1 = (nnodes + 127) / 128;
        phase1_kernel<<<blocks1, 256, 0, stream>>>(
            z, root_w, root_b, w1bf, lin1_b, w2bf, lin2_b, btbf,
            norm_g, norm_b, T1, T2, nnodes);

        const long long thr2 = (long long)E * 8;
        const int blocks2 = (int)((thr2 + 255) / 256);
        phase2_kernel<<<blocks2, 256, 0, stream>>>(arcs, T1, T2, bil_b, out, E);
    } else {
        edge_direct_kernel<<<8192, 256, 0, stream>>>(
            z, arcs, root_w, root_b, lin1_w, lin1_b, lin2_w, lin2_b,
            bil_w, bil_b, norm_g, norm_b, out, E, nnodes);
    }
}

// Round 19
// 127.405 us; speedup vs baseline: 1.0018x; 1.0018x over previous
//
#include <hip/hip_runtime.h>
#include <hip/hip_bf16.h>
#include <hip/hip_fp16.h>

typedef unsigned short u16;
typedef unsigned int u32;

typedef float f32x4 __attribute__((ext_vector_type(4)));
typedef _Float16 f16x8 __attribute__((ext_vector_type(8)));
typedef _Float16 f16x2 __attribute__((ext_vector_type(2)));

#define HDIM 64
#define EPS 1e-5f
#define XROW 68      // u16 stride per LDS row (8B-aligned, bank-spread)

// ---------- helpers ----------

__device__ __forceinline__ float wave_sum64(float v) {
    v += __shfl_xor(v, 1, 64);
    v += __shfl_xor(v, 2, 64);
    v += __shfl_xor(v, 4, 64);
    v += __shfl_xor(v, 8, 64);
    v += __shfl_xor(v, 16, 64);
    v += __shfl_xor(v, 32, 64);
    return v;
}

__device__ __forceinline__ float bcast(float v, int k) {
    return __int_as_float(__builtin_amdgcn_readlane(__float_as_int(v), k));
}

// f32 -> fp16 bits (v_cvt_f16_f32, round-nearest-even)
__device__ __forceinline__ u16 f2h(float f) {
    return __half_as_ushort(__float2half(f));
}

__device__ __forceinline__ u32 pack2h(float e0, float e1) {
    return (u32)f2h(e0) | ((u32)f2h(e1) << 16);
}

// dot of two fp16x2 words with f32 accumulate
__device__ __forceinline__ float dot2h(u32 a, u32 b, float c) {
    union { u32 u; f16x2 h; } ua, ub;
    ua.u = a; ub.u = b;
#if __has_builtin(__builtin_amdgcn_fdot2)
    return __builtin_amdgcn_fdot2(ua.h, ub.h, c, false);
#else
    c = fmaf((float)ua.h.x, (float)ub.h.x, c);
    c = fmaf((float)ua.h.y, (float)ub.h.y, c);
    return c;
#endif
}

// ---------- prep: fp16 weight copies (bil_w transposed, natural) ----------
__global__ __launch_bounds__(256) void prep_kernel(
    const float* __restrict__ lin1_w, const float* __restrict__ lin2_w,
    const float* __restrict__ bil_w,
    u16* __restrict__ w1h, u16* __restrict__ w2h, u16* __restrict__ bth)
{
    const int gtid = blockIdx.x * 256 + threadIdx.x;
    for (int i = gtid; i < 4096; i += gridDim.x * 256) {
        w1h[i] = f2h(lin1_w[i]);              // row-major [h][k]
        w2h[i] = f2h(lin2_w[i]);
        const int g = i >> 6, h = i & 63;
        bth[i] = f2h(bil_w[h * 64 + g]);      // bth[g][h] = bil_w[h][g]
    }
}

// ---------- MFMA fragment loaders (r8-validated mappings; layout is
// dtype-independent, so fp16 uses the same lane->element maps) ----------
// A (M=16 x K=32), tile m: lane l holds row 16m + l%16, k = 8*(l>>4)+i (+32s)
__device__ __forceinline__ f16x8 load_afrag(const u16* Xs, int l, int m, int s) {
    const int row = 16 * m + (l & 15);
    const int k0  = 8 * (l >> 4) + 32 * s;
    union { uint2 u[2]; f16x8 f; } c;
    c.u[0] = *(const uint2*)&Xs[row * XROW + k0];
    c.u[1] = *(const uint2*)&Xs[row * XROW + k0 + 4];
    return c.f;
}

// B (K=32 x N=16): lane l holds col l%16 (+16t), k = 8*(l>>4)+32s.
__device__ __forceinline__ f16x8 load_bfrag(const u16* __restrict__ W,
                                            int l, int t, int s) {
    const int n  = (l & 15) + 16 * t;
    const int k0 = 8 * (l >> 4) + 32 * s;
    return *(const f16x8*)&W[n * 64 + k0];
}

// relu(acc + bias) then LN across h (4 tiles x 4 regs, 16-lane reduce).
// C/D layout: col = l&15 (+16t), row(node) = (l>>4)*4 + reg
__device__ __forceinline__ void relu_ln_acc(f32x4* acc, const float* biasv,
                                            const float* gv, const float* bvv) {
    float s[4] = {0.f,0.f,0.f,0.f}, q[4] = {0.f,0.f,0.f,0.f};
#pragma unroll
    for (int t = 0; t < 4; ++t)
#pragma unroll
        for (int j = 0; j < 4; ++j) {
            float v = fmaxf(acc[t][j] + biasv[t], 0.f);
            acc[t][j] = v;
            s[j] += v; q[j] = fmaf(v, v, q[j]);
        }
#pragma unroll
    for (int j = 0; j < 4; ++j) {
#pragma unroll
        for (int m = 1; m < 16; m <<= 1) {
            s[j] += __shfl_xor(s[j], m, 64);
            q[j] += __shfl_xor(q[j], m, 64);
        }
        const float mu = s[j] * 0.015625f;
        const float rs = rsqrtf(q[j] * 0.015625f - mu * mu + EPS);
#pragma unroll
        for (int t = 0; t < 4; ++t)
            acc[t][j] = (acc[t][j] - mu) * rs * gv[t] + bvv[t];
    }
}

// scatter acc (fp16) into LDS rows [16m + node][h]  (natural layout)
__device__ __forceinline__ void acc_to_lds(u16* Xs, const f32x4* acc, int l, int m) {
    const int hcol = l & 15;
#pragma unroll
    for (int j = 0; j < 4; ++j) {
        const int row = 16 * m + (l >> 4) * 4 + j;
#pragma unroll
        for (int t = 0; t < 4; ++t)
            Xs[row * XROW + hcol + 16 * t] = f2h(acc[t][j]);
    }
}

// coalesced copy of 32 LDS rows (64 fp16 each) to global table; 2 lanes/row
__device__ __forceinline__ void lds_to_global32(u16* __restrict__ T, const u16* Xs,
                                                int l, int n0, int nnodes) {
    const int row  = l >> 1;
    const int node = n0 + row;
    if (node >= nnodes) return;
    const int c0 = (l & 1) * 32;
    const u16* src = &Xs[row * XROW + c0];
    uint2 p[8];
#pragma unroll
    for (int j = 0; j < 8; ++j) p[j] = *(const uint2*)&src[4*j];
    uint4* d = (uint4*)(T + (size_t)node * HDIM + c0);
    d[0] = make_uint4(p[0].x, p[0].y, p[1].x, p[1].y);
    d[1] = make_uint4(p[2].x, p[2].y, p[3].x, p[3].y);
    d[2] = make_uint4(p[4].x, p[4].y, p[5].x, p[5].y);
    d[3] = make_uint4(p[6].x, p[6].y, p[7].x, p[7].y);
}

// ---------- phase 1: MFMA per-node transform -> fp16 tables ----------
// One wave per 32 nodes; direct z->fragment loads; barriers at every
// cross-lane LDS transition (r17 hardening). NO waves-per-EU bound:
// launch_bounds(256,2) empirically perturbs codegen rounding (r15/16/18).
__global__ __launch_bounds__(256) void phase1_kernel(
    const float* __restrict__ z,
    const float* __restrict__ root_w, const float* __restrict__ root_b,
    const u16* __restrict__ w1h, const float* __restrict__ lin1_b,
    const u16* __restrict__ w2h, const float* __restrict__ lin2_b,
    const u16* __restrict__ bth,
    const float* __restrict__ norm_g, const float* __restrict__ norm_b,
    u16* __restrict__ T1, u16* __restrict__ T2, int nnodes)
{
    __shared__ u16 XsAll[4][32 * XROW];      // 17.4 KB/block (bounce buffer)

    const int tid = threadIdx.x;
    const int wid = tid >> 6;
    const int l   = tid & 63;
    u16* Xs = XsAll[wid];

    const int n0 = (blockIdx.x * 4 + wid) * 32;

    const int arow = l & 15;
    const int kg   = (l >> 4) * 8;           // this lane's k-base (s=0)

    // per-lane norm params for its own k slices (shared across m tiles)
    float4 gk0 = *(const float4*)&norm_g[kg];
    float4 gk1 = *(const float4*)&norm_g[kg + 4];
    float4 gk2 = *(const float4*)&norm_g[kg + 32];
    float4 gk3 = *(const float4*)&norm_g[kg + 36];
    float4 bk0 = *(const float4*)&norm_b[kg];
    float4 bk1 = *(const float4*)&norm_b[kg + 4];
    float4 bk2 = *(const float4*)&norm_b[kg + 32];
    float4 bk3 = *(const float4*)&norm_b[kg + 36];

    // ---- direct z -> LN -> A fragments (registers only) ----
    f16x8 a[2][2];
#pragma unroll
    for (int m = 0; m < 2; ++m) {
        const int node = n0 + 16 * m + arow;
        float r[16];
        if (node == 0) {
#pragma unroll
            for (int q = 0; q < 2; ++q) {
                const float4 aw = *(const float4*)&root_w[kg + 4*q];
                const float4 ab = *(const float4*)&root_b[kg + 4*q];
                r[4*q]   = aw.x + ab.x; r[4*q+1] = aw.y + ab.y;
                r[4*q+2] = aw.z + ab.z; r[4*q+3] = aw.w + ab.w;
                const float4 cw = *(const float4*)&root_w[kg + 32 + 4*q];
                const float4 cb = *(const float4*)&root_b[kg + 32 + 4*q];
                r[8+4*q]   = cw.x + cb.x; r[8+4*q+1] = cw.y + cb.y;
                r[8+4*q+2] = cw.z + cb.z; r[8+4*q+3] = cw.w + cb.w;
            }
        } else if (node < nnodes) {
            const float* zp = z + (size_t)(node - 1) * HDIM + kg;
            const float4 v0 = *(const float4*)(zp);
            const float4 v1 = *(const float4*)(zp + 4);
            const float4 v2 = *(const float4*)(zp + 32);
            const float4 v3 = *(const float4*)(zp + 36);
            r[0]=v0.x; r[1]=v0.y; r[2]=v0.z; r[3]=v0.w;
            r[4]=v1.x; r[5]=v1.y; r[6]=v1.z; r[7]=v1.w;
            r[8]=v2.x; r[9]=v2.y; r[10]=v2.z; r[11]=v2.w;
            r[12]=v3.x; r[13]=v3.y; r[14]=v3.z; r[15]=v3.w;
        } else {
#pragma unroll
            for (int k = 0; k < 16; ++k) r[k] = 0.f;
        }
        // row stats: 4 lanes (arow, +16, +32, +48) hold the 64 elements
        float s = 0.f, sq = 0.f;
#pragma unroll
        for (int k = 0; k < 16; ++k) { s += r[k]; sq = fmaf(r[k], r[k], sq); }
        s += __shfl_xor(s, 16, 64);  sq += __shfl_xor(sq, 16, 64);
        s += __shfl_xor(s, 32, 64);  sq += __shfl_xor(sq, 32, 64);
        const float mu = s * 0.015625f;
        const float rs = rsqrtf(sq * 0.015625f - mu * mu + EPS);

        const float gA[8] = {gk0.x,gk0.y,gk0.z,gk0.w, gk1.x,gk1.y,gk1.z,gk1.w};
        const float bA[8] = {bk0.x,bk0.y,bk0.z,bk0.w, bk1.x,bk1.y,bk1.z,bk1.w};
        const float gB[8] = {gk2.x,gk2.y,gk2.z,gk2.w, gk3.x,gk3.y,gk3.z,gk3.w};
        const float bB[8] = {bk2.x,bk2.y,bk2.z,bk2.w, bk3.x,bk3.y,bk3.z,bk3.w};
        union { u32 u[4]; f16x8 f; } c0, c1;
#pragma unroll
        for (int j = 0; j < 4; ++j) {
            c0.u[j] = pack2h((r[2*j]   - mu) * rs * gA[2*j]   + bA[2*j],
                             (r[2*j+1] - mu) * rs * gA[2*j+1] + bA[2*j+1]);
            c1.u[j] = pack2h((r[8+2*j]   - mu) * rs * gB[2*j]   + bB[2*j],
                             (r[8+2*j+1] - mu) * rs * gB[2*j+1] + bB[2*j+1]);
        }
        a[m][0] = c0.f;
        a[m][1] = c1.f;
    }

    // ---- per-lane output-column constants ----
    const int hcol = l & 15;
    float gv[4], bv[4], b1v[4], b2v[4];
#pragma unroll
    for (int t = 0; t < 4; ++t) {
        gv[t]  = norm_g[hcol + 16*t];
        bv[t]  = norm_b[hcol + 16*t];
        b1v[t] = lin1_b[hcol + 16*t];
        b2v[t] = lin2_b[hcol + 16*t];
    }

    // ---- y2 = zz@W2^T, y1 = zz@W1^T (B frags shared across tiles) ----
    f32x4 acc2[2][4], acc1[2][4];
#pragma unroll
    for (int t = 0; t < 4; ++t) {
        const f16x8 b0 = load_bfrag(w2h, l, t, 0);
        const f16x8 b1 = load_bfrag(w2h, l, t, 1);
#pragma unroll
        for (int m = 0; m < 2; ++m) {
            f32x4 c = {0.f, 0.f, 0.f, 0.f};
            c = __builtin_amdgcn_mfma_f32_16x16x32_f16(a[m][0], b0, c, 0, 0, 0);
            c = __builtin_amdgcn_mfma_f32_16x16x32_f16(a[m][1], b1, c, 0, 0, 0);
            acc2[m][t] = c;
        }
    }
#pragma unroll
    for (int t = 0; t < 4; ++t) {
        const f16x8 b0 = load_bfrag(w1h, l, t, 0);
        const f16x8 b1 = load_bfrag(w1h, l, t, 1);
#pragma unroll
        for (int m = 0; m < 2; ++m) {
            f32x4 c = {0.f, 0.f, 0.f, 0.f};
            c = __builtin_amdgcn_mfma_f32_16x16x32_f16(a[m][0], b0, c, 0, 0, 0);
            c = __builtin_amdgcn_mfma_f32_16x16x32_f16(a[m][1], b1, c, 0, 0, 0);
            acc1[m][t] = c;
        }
    }

    // ---- x2 -> Xs -> T2 ----
    relu_ln_acc(acc2[0], b2v, gv, bv);
    relu_ln_acc(acc2[1], b2v, gv, bv);
    acc_to_lds(Xs, acc2[0], l, 0);
    acc_to_lds(Xs, acc2[1], l, 1);
    __syncthreads();                         // RAW: writes visible to all lanes
    lds_to_global32(T2, Xs, l, n0, nnodes);
    __syncthreads();                         // WAR: reads done before overwrite

    // ---- x1 -> Xs ----
    relu_ln_acc(acc1[0], b1v, gv, bv);
    relu_ln_acc(acc1[1], b1v, gv, bv);
    acc_to_lds(Xs, acc1[0], l, 0);
    acc_to_lds(Xs, acc1[1], l, 1);
    __syncthreads();                         // RAW
#pragma unroll
    for (int m = 0; m < 2; ++m) {
        a[m][0] = load_afrag(Xs, l, m, 0);
        a[m][1] = load_afrag(Xs, l, m, 1);
    }
    __syncthreads();                         // WAR

    // ---- t = x1 @ bil_w -> T1 (no bias/relu/LN) ----
    f32x4 acc3[2][4];
#pragma unroll
    for (int t = 0; t < 4; ++t) {
        const f16x8 b0 = load_bfrag(bth, l, t, 0);
        const f16x8 b1 = load_bfrag(bth, l, t, 1);
#pragma unroll
        for (int m = 0; m < 2; ++m) {
            f32x4 c = {0.f, 0.f, 0.f, 0.f};
            c = __builtin_amdgcn_mfma_f32_16x16x32_f16(a[m][0], b0, c, 0, 0, 0);
            c = __builtin_amdgcn_mfma_f32_16x16x32_f16(a[m][1], b1, c, 0, 0, 0);
            acc3[m][t] = c;
        }
    }
    acc_to_lds(Xs, acc3[0], l, 0);
    acc_to_lds(Xs, acc3[1], l, 1);
    __syncthreads();                         // RAW
    lds_to_global32(T1, Xs, l, n0, nnodes);
}

// ---------- phase 2: per-edge gather + 64-dot (fp16, fdot2) ----------
__global__ __launch_bounds__(256) void phase2_kernel(
    const int* __restrict__ arcs,
    const u16* __restrict__ T1, const u16* __restrict__ T2,
    const float* __restrict__ bil_b,
    float* __restrict__ out, int E)
{
    const int tid = blockIdx.x * 256 + threadIdx.x;
    const int e = tid >> 3;
    if (e >= E) return;
    const int l8 = tid & 7;

    const int i0 = arcs[2 * e];
    const int i1 = arcs[2 * e + 1];

    const uint4* p1 = (const uint4*)(T1 + (size_t)i0 * HDIM) + l8;
    const uint4* p2 = (const uint4*)(T2 + (size_t)i1 * HDIM) + l8;
    uint4 u = *p1;
    uint4 v = *p2;

    float s = 0.f;
    s = dot2h(u.x, v.x, s);
    s = dot2h(u.y, v.y, s);
    s = dot2h(u.z, v.z, s);
    s = dot2h(u.w, v.w, s);

    s += __shfl_xor(s, 1, 64);
    s += __shfl_xor(s, 2, 64);
    s += __shfl_xor(s, 4, 64);
    if (l8 == 0) out[e] = s + bil_b[0];
}

// ---------- fallback: per-edge full recompute (if ws too small) ----------
__device__ __forceinline__ float lnorm_w(float v, float g, float b) {
    float mu = wave_sum64(v) * 0.015625f;
    float d  = v - mu;
    float var = wave_sum64(d * d) * 0.015625f;
    return d * rsqrtf(var + EPS) * g + b;
}

__global__ __launch_bounds__(256) void edge_direct_kernel(
    const float* __restrict__ z, const int* __restrict__ arcs,
    const float* __restrict__ root_w, const float* __restrict__ root_b,
    const float* __restrict__ lin1_w, const float* __restrict__ lin1_b,
    const float* __restrict__ lin2_w, const float* __restrict__ lin2_b,
    const float* __restrict__ bil_w, const float* __restrict__ bil_b,
    const float* __restrict__ norm_g, const float* __restrict__ norm_b,
    float* __restrict__ out, int E, int nnodes)
{
    __shared__ float W1t[4096], W2t[4096], Bs[4096];
    const int tid = threadIdx.x;
    for (int i = tid; i < 4096; i += 256) {
        int h = i >> 6, k = i & 63;
        W1t[(k << 6) | h] = lin1_w[i];
        W2t[(k << 6) | h] = lin2_w[i];
        Bs[i] = bil_w[i];
    }
    __syncthreads();

    const int lane = tid & 63;
    const float g  = norm_g[lane], bt = norm_b[lane];
    const float b1 = lin1_b[lane], b2 = lin2_b[lane];
    const float rootv = root_w[lane] + root_b[lane];

    const int gwave = (blockIdx.x * 256 + tid) >> 6;
    const int nwaves = (gridDim.x * 256) >> 6;

    for (int e = gwave; e < E; e += nwaves) {
        int i0 = arcs[2 * e], i1 = arcs[2 * e + 1];
        float v0 = (i0 == 0) ? rootv : z[(size_t)(i0 - 1) * HDIM + lane];
        float v1 = (i1 == 0) ? rootv : z[(size_t)(i1 - 1) * HDIM + lane];
        float l0 = lnorm_w(v0, g, bt);
        float l1 = lnorm_w(v1, g, bt);
        float a1 = 0.f, a2 = 0.f;
#pragma unroll
        for (int k = 0; k < 64; ++k) {
            a1 = fmaf(bcast(l0, k), W1t[(k << 6) | lane], a1);
            a2 = fmaf(bcast(l1, k), W2t[(k << 6) | lane], a2);
        }
        float x1 = lnorm_w(fmaxf(a1 + b1, 0.f), g, bt);
        float x2 = lnorm_w(fmaxf(a2 + b2, 0.f), g, bt);
        float w1 = 0.f;
#pragma unroll
        for (int h = 0; h < 64; ++h)
            w1 = fmaf(bcast(x1, h), Bs[(h << 6) | lane], w1);
        float sc = wave_sum64(w1 * x2);
        if (lane == 0) out[e] = sc + bil_b[0];
    }
}

// ---------- launch ----------
extern "C" void kernel_launch(void* const* d_in, const int* in_sizes, int n_in,
                              void* d_out, int out_size, void* d_ws, size_t ws_size,
                              hipStream_t stream) {
    const float* z      = (const float*)d_in[0];
    const int*   arcs   = (const int*)  d_in[1];
    const float* root_w = (const float*)d_in[2];
    const float* root_b = (const float*)d_in[3];
    const float* lin1_w = (const float*)d_in[4];
    const float* lin1_b = (const float*)d_in[5];
    const float* lin2_w = (const float*)d_in[6];
    const float* lin2_b = (const float*)d_in[7];
    const float* bil_w  = (const float*)d_in[8];
    const float* bil_b  = (const float*)d_in[9];
    const float* norm_g = (const float*)d_in[10];
    const float* norm_b = (const float*)d_in[11];
    float* out = (float*)d_out;

    const int E      = in_sizes[1] / 2;
    const int nnodes = in_sizes[0] / HDIM + 1;

    const size_t tbl  = (size_t)nnodes * HDIM * sizeof(u16);
    const size_t need = 2 * tbl + 3 * 4096 * sizeof(u16);

    if (ws_size >= need) {
        u16* T1  = (u16*)d_ws;
        u16* T2  = (u16*)((char*)d_ws + tbl);
        u16* w1h = (u16*)((char*)d_ws + 2 * tbl);
        u16* w2h = w1h + 4096;
        u16* bth = w2h + 4096;

        prep_kernel<<<16, 256, 0, stream>>>(lin1_w, lin2_w, bil_w, w1h, w2h, bth);

        const int blocks1 = (nnodes + 127) / 128;
        phase1_kernel<<<blocks1, 256, 0, stream>>>(
            z, root_w, root_b, w1h, lin1_b, w2h, lin2_b, bth,
            norm_g, norm_b, T1, T2, nnodes);

        const long long thr2 = (long long)E * 8;
        const int blocks2 = (int)((thr2 + 255) / 256);
        phase2_kernel<<<blocks2, 256, 0, stream>>>(arcs, T1, T2, bil_b, out, E);
    } else {
        edge_direct_kernel<<<8192, 256, 0, stream>>>(
            z, arcs, root_w, root_b, lin1_w, lin1_b, lin2_w, lin2_b,
            bil_w, bil_b, norm_g, norm_b, out, E, nnodes);
    }
}

// Round 21
// 123.717 us; speedup vs baseline: 1.0317x; 1.0298x over previous
//
#include <hip/hip_runtime.h>
#include <hip/hip_bf16.h>
#include <hip/hip_fp16.h>

typedef unsigned short u16;
typedef unsigned int u32;

typedef float f32x4 __attribute__((ext_vector_type(4)));
typedef _Float16 f16x8 __attribute__((ext_vector_type(8)));
typedef _Float16 f16x2 __attribute__((ext_vector_type(2)));

#define HDIM 64
#define EPS 1e-5f
#define XROW 68      // u16 stride per LDS row (8B-aligned, bank-spread)

// ---------- helpers ----------

__device__ __forceinline__ float wave_sum64(float v) {
    v += __shfl_xor(v, 1, 64);
    v += __shfl_xor(v, 2, 64);
    v += __shfl_xor(v, 4, 64);
    v += __shfl_xor(v, 8, 64);
    v += __shfl_xor(v, 16, 64);
    v += __shfl_xor(v, 32, 64);
    return v;
}

__device__ __forceinline__ float bcast(float v, int k) {
    return __int_as_float(__builtin_amdgcn_readlane(__float_as_int(v), k));
}

// f32 -> fp16 bits (v_cvt_f16_f32, round-nearest-even)
__device__ __forceinline__ u16 f2h(float f) {
    return __half_as_ushort(__float2half(f));
}

__device__ __forceinline__ u32 pack2h(float e0, float e1) {
    return (u32)f2h(e0) | ((u32)f2h(e1) << 16);
}

// dot of two fp16x2 words with f32 accumulate
__device__ __forceinline__ float dot2h(u32 a, u32 b, float c) {
    union { u32 u; f16x2 h; } ua, ub;
    ua.u = a; ub.u = b;
#if __has_builtin(__builtin_amdgcn_fdot2)
    return __builtin_amdgcn_fdot2(ua.h, ub.h, c, false);
#else
    c = fmaf((float)ua.h.x, (float)ub.h.x, c);
    c = fmaf((float)ua.h.y, (float)ub.h.y, c);
    return c;
#endif
}

// ---------- prep: fp16 weight copies (bil_w transposed, natural) ----------
__global__ __launch_bounds__(256) void prep_kernel(
    const float* __restrict__ lin1_w, const float* __restrict__ lin2_w,
    const float* __restrict__ bil_w,
    u16* __restrict__ w1h, u16* __restrict__ w2h, u16* __restrict__ bth)
{
    const int gtid = blockIdx.x * 256 + threadIdx.x;
    for (int i = gtid; i < 4096; i += gridDim.x * 256) {
        w1h[i] = f2h(lin1_w[i]);              // row-major [h][k]
        w2h[i] = f2h(lin2_w[i]);
        const int g = i >> 6, h = i & 63;
        bth[i] = f2h(bil_w[h * 64 + g]);      // bth[g][h] = bil_w[h][g]
    }
}

// ---------- MFMA fragment loaders (r8-validated mappings) ----------
// A (M=16 x K=32), tile m: lane l holds row 16m + l%16, k = 8*(l>>4)+i (+32s)
__device__ __forceinline__ f16x8 load_afrag(const u16* Xs, int l, int m, int s) {
    const int row = 16 * m + (l & 15);
    const int k0  = 8 * (l >> 4) + 32 * s;
    union { uint2 u[2]; f16x8 f; } c;
    c.u[0] = *(const uint2*)&Xs[row * XROW + k0];
    c.u[1] = *(const uint2*)&Xs[row * XROW + k0 + 4];
    return c.f;
}

// B (K=32 x N=16): lane l holds col l%16 (+16t), k = 8*(l>>4)+32s.
__device__ __forceinline__ f16x8 load_bfrag(const u16* __restrict__ W,
                                            int l, int t, int s) {
    const int n  = (l & 15) + 16 * t;
    const int k0 = 8 * (l >> 4) + 32 * s;
    return *(const f16x8*)&W[n * 64 + k0];
}

// relu(acc + bias) then LN across h (4 tiles x 4 regs, 16-lane reduce).
// C/D layout: col = l&15 (+16t), row(node) = (l>>4)*4 + reg
__device__ __forceinline__ void relu_ln_acc(f32x4* acc, const float* biasv,
                                            const float* gv, const float* bvv) {
    float s[4] = {0.f,0.f,0.f,0.f}, q[4] = {0.f,0.f,0.f,0.f};
#pragma unroll
    for (int t = 0; t < 4; ++t)
#pragma unroll
        for (int j = 0; j < 4; ++j) {
            float v = fmaxf(acc[t][j] + biasv[t], 0.f);
            acc[t][j] = v;
            s[j] += v; q[j] = fmaf(v, v, q[j]);
        }
#pragma unroll
    for (int j = 0; j < 4; ++j) {
#pragma unroll
        for (int m = 1; m < 16; m <<= 1) {
            s[j] += __shfl_xor(s[j], m, 64);
            q[j] += __shfl_xor(q[j], m, 64);
        }
        const float mu = s[j] * 0.015625f;
        const float rs = rsqrtf(q[j] * 0.015625f - mu * mu + EPS);
#pragma unroll
        for (int t = 0; t < 4; ++t)
            acc[t][j] = (acc[t][j] - mu) * rs * gv[t] + bvv[t];
    }
}

// scatter acc (fp16) into LDS rows [16m + node][h]  (natural layout)
__device__ __forceinline__ void acc_to_lds(u16* Xs, const f32x4* acc, int l, int m) {
    const int hcol = l & 15;
#pragma unroll
    for (int j = 0; j < 4; ++j) {
        const int row = 16 * m + (l >> 4) * 4 + j;
#pragma unroll
        for (int t = 0; t < 4; ++t)
            Xs[row * XROW + hcol + 16 * t] = f2h(acc[t][j]);
    }
}

// coalesced copy of 32 LDS rows (64 fp16 each) to global table; 2 lanes/row
__device__ __forceinline__ void lds_to_global32(u16* __restrict__ T, const u16* Xs,
                                                int l, int n0, int nnodes) {
    const int row  = l >> 1;
    const int node = n0 + row;
    if (node >= nnodes) return;
    const int c0 = (l & 1) * 32;
    const u16* src = &Xs[row * XROW + c0];
    uint2 p[8];
#pragma unroll
    for (int j = 0; j < 8; ++j) p[j] = *(const uint2*)&src[4*j];
    uint4* d = (uint4*)(T + (size_t)node * HDIM + c0);
    d[0] = make_uint4(p[0].x, p[0].y, p[1].x, p[1].y);
    d[1] = make_uint4(p[2].x, p[2].y, p[3].x, p[3].y);
    d[2] = make_uint4(p[4].x, p[4].y, p[5].x, p[5].y);
    d[3] = make_uint4(p[6].x, p[6].y, p[7].x, p[7].y);
}

// ---------- phase 1: MFMA per-node transform -> fp16 tables ----------
// One wave per 32 nodes; direct z->fragment loads; barriers at every
// cross-lane LDS transition. SEQUENTIAL accumulator lifetimes (one GEMM's
// acc live at a time, scoped) so the compiler naturally allocates <=128
// VGPR -> 2 waves/SIMD. NO waves-per-EU launch_bounds: that attribute
// caused cross-call nondeterminism 3/3 times (r15/r18/r20) - banned.
__global__ __launch_bounds__(256) void phase1_kernel(
    const float* __restrict__ z,
    const float* __restrict__ root_w, const float* __restrict__ root_b,
    const u16* __restrict__ w1h, const float* __restrict__ lin1_b,
    const u16* __restrict__ w2h, const float* __restrict__ lin2_b,
    const u16* __restrict__ bth,
    const float* __restrict__ norm_g, const float* __restrict__ norm_b,
    u16* __restrict__ T1, u16* __restrict__ T2, int nnodes)
{
    __shared__ u16 XsAll[4][32 * XROW];      // 17.4 KB/block (bounce buffer)

    const int tid = threadIdx.x;
    const int wid = tid >> 6;
    const int l   = tid & 63;
    u16* Xs = XsAll[wid];

    const int n0 = (blockIdx.x * 4 + wid) * 32;

    const int arow = l & 15;
    const int kg   = (l >> 4) * 8;           // this lane's k-base (s=0)

    // per-lane norm params for its own k slices (shared across m tiles)
    float4 gk0 = *(const float4*)&norm_g[kg];
    float4 gk1 = *(const float4*)&norm_g[kg + 4];
    float4 gk2 = *(const float4*)&norm_g[kg + 32];
    float4 gk3 = *(const float4*)&norm_g[kg + 36];
    float4 bk0 = *(const float4*)&norm_b[kg];
    float4 bk1 = *(const float4*)&norm_b[kg + 4];
    float4 bk2 = *(const float4*)&norm_b[kg + 32];
    float4 bk3 = *(const float4*)&norm_b[kg + 36];

    // ---- direct z -> LN -> A fragments (registers only) ----
    f16x8 a[2][2];
#pragma unroll
    for (int m = 0; m < 2; ++m) {
        const int node = n0 + 16 * m + arow;
        float r[16];
        if (node == 0) {
#pragma unroll
            for (int q = 0; q < 2; ++q) {
                const float4 aw = *(const float4*)&root_w[kg + 4*q];
                const float4 ab = *(const float4*)&root_b[kg + 4*q];
                r[4*q]   = aw.x + ab.x; r[4*q+1] = aw.y + ab.y;
                r[4*q+2] = aw.z + ab.z; r[4*q+3] = aw.w + ab.w;
                const float4 cw = *(const float4*)&root_w[kg + 32 + 4*q];
                const float4 cb = *(const float4*)&root_b[kg + 32 + 4*q];
                r[8+4*q]   = cw.x + cb.x; r[8+4*q+1] = cw.y + cb.y;
                r[8+4*q+2] = cw.z + cb.z; r[8+4*q+3] = cw.w + cb.w;
            }
        } else if (node < nnodes) {
            const float* zp = z + (size_t)(node - 1) * HDIM + kg;
            const float4 v0 = *(const float4*)(zp);
            const float4 v1 = *(const float4*)(zp + 4);
            const float4 v2 = *(const float4*)(zp + 32);
            const float4 v3 = *(const float4*)(zp + 36);
            r[0]=v0.x; r[1]=v0.y; r[2]=v0.z; r[3]=v0.w;
            r[4]=v1.x; r[5]=v1.y; r[6]=v1.z; r[7]=v1.w;
            r[8]=v2.x; r[9]=v2.y; r[10]=v2.z; r[11]=v2.w;
            r[12]=v3.x; r[13]=v3.y; r[14]=v3.z; r[15]=v3.w;
        } else {
#pragma unroll
            for (int k = 0; k < 16; ++k) r[k] = 0.f;
        }
        // row stats: 4 lanes (arow, +16, +32, +48) hold the 64 elements
        float s = 0.f, sq = 0.f;
#pragma unroll
        for (int k = 0; k < 16; ++k) { s += r[k]; sq = fmaf(r[k], r[k], sq); }
        s += __shfl_xor(s, 16, 64);  sq += __shfl_xor(sq, 16, 64);
        s += __shfl_xor(s, 32, 64);  sq += __shfl_xor(sq, 32, 64);
        const float mu = s * 0.015625f;
        const float rs = rsqrtf(sq * 0.015625f - mu * mu + EPS);

        const float gA[8] = {gk0.x,gk0.y,gk0.z,gk0.w, gk1.x,gk1.y,gk1.z,gk1.w};
        const float bA[8] = {bk0.x,bk0.y,bk0.z,bk0.w, bk1.x,bk1.y,bk1.z,bk1.w};
        const float gB[8] = {gk2.x,gk2.y,gk2.z,gk2.w, gk3.x,gk3.y,gk3.z,gk3.w};
        const float bB[8] = {bk2.x,bk2.y,bk2.z,bk2.w, bk3.x,bk3.y,bk3.z,bk3.w};
        union { u32 u[4]; f16x8 f; } c0, c1;
#pragma unroll
        for (int j = 0; j < 4; ++j) {
            c0.u[j] = pack2h((r[2*j]   - mu) * rs * gA[2*j]   + bA[2*j],
                             (r[2*j+1] - mu) * rs * gA[2*j+1] + bA[2*j+1]);
            c1.u[j] = pack2h((r[8+2*j]   - mu) * rs * gB[2*j]   + bB[2*j],
                             (r[8+2*j+1] - mu) * rs * gB[2*j+1] + bB[2*j+1]);
        }
        a[m][0] = c0.f;
        a[m][1] = c1.f;
    }

    // ---- per-lane output-column constants ----
    const int hcol = l & 15;
    float gv[4], bv[4], b1v[4], b2v[4];
#pragma unroll
    for (int t = 0; t < 4; ++t) {
        gv[t]  = norm_g[hcol + 16*t];
        bv[t]  = norm_b[hcol + 16*t];
        b1v[t] = lin1_b[hcol + 16*t];
        b2v[t] = lin2_b[hcol + 16*t];
    }

    // ---- stage 1 (scoped acc): x2 = LN(relu(zz@W2^T+b2)) -> T2 ----
    {
        f32x4 acc[2][4];
#pragma unroll
        for (int t = 0; t < 4; ++t) {
            const f16x8 b0 = load_bfrag(w2h, l, t, 0);
            const f16x8 b1 = load_bfrag(w2h, l, t, 1);
#pragma unroll
            for (int m = 0; m < 2; ++m) {
                f32x4 c = {0.f, 0.f, 0.f, 0.f};
                c = __builtin_amdgcn_mfma_f32_16x16x32_f16(a[m][0], b0, c, 0, 0, 0);
                c = __builtin_amdgcn_mfma_f32_16x16x32_f16(a[m][1], b1, c, 0, 0, 0);
                acc[m][t] = c;
            }
        }
        relu_ln_acc(acc[0], b2v, gv, bv);
        relu_ln_acc(acc[1], b2v, gv, bv);
        acc_to_lds(Xs, acc[0], l, 0);
        acc_to_lds(Xs, acc[1], l, 1);
    }
    __syncthreads();                         // RAW: writes visible to all lanes
    lds_to_global32(T2, Xs, l, n0, nnodes);
    __syncthreads();                         // WAR: reads done before overwrite

    // ---- stage 2 (scoped acc): x1 = LN(relu(zz@W1^T+b1)) -> Xs ----
    {
        f32x4 acc[2][4];
#pragma unroll
        for (int t = 0; t < 4; ++t) {
            const f16x8 b0 = load_bfrag(w1h, l, t, 0);
            const f16x8 b1 = load_bfrag(w1h, l, t, 1);
#pragma unroll
            for (int m = 0; m < 2; ++m) {
                f32x4 c = {0.f, 0.f, 0.f, 0.f};
                c = __builtin_amdgcn_mfma_f32_16x16x32_f16(a[m][0], b0, c, 0, 0, 0);
                c = __builtin_amdgcn_mfma_f32_16x16x32_f16(a[m][1], b1, c, 0, 0, 0);
                acc[m][t] = c;
            }
        }
        relu_ln_acc(acc[0], b1v, gv, bv);
        relu_ln_acc(acc[1], b1v, gv, bv);
        acc_to_lds(Xs, acc[0], l, 0);
        acc_to_lds(Xs, acc[1], l, 1);
    }
    __syncthreads();                         // RAW
#pragma unroll
    for (int m = 0; m < 2; ++m) {
        a[m][0] = load_afrag(Xs, l, m, 0);
        a[m][1] = load_afrag(Xs, l, m, 1);
    }
    __syncthreads();                         // WAR

    // ---- stage 3 (scoped acc): t = x1 @ bil_w -> T1 (no bias/relu/LN) ----
    {
        f32x4 acc[2][4];
#pragma unroll
        for (int t = 0; t < 4; ++t) {
            const f16x8 b0 = load_bfrag(bth, l, t, 0);
            const f16x8 b1 = load_bfrag(bth, l, t, 1);
#pragma unroll
            for (int m = 0; m < 2; ++m) {
                f32x4 c = {0.f, 0.f, 0.f, 0.f};
                c = __builtin_amdgcn_mfma_f32_16x16x32_f16(a[m][0], b0, c, 0, 0, 0);
                c = __builtin_amdgcn_mfma_f32_16x16x32_f16(a[m][1], b1, c, 0, 0, 0);
                acc[m][t] = c;
            }
        }
        acc_to_lds(Xs, acc[0], l, 0);
        acc_to_lds(Xs, acc[1], l, 1);
    }
    __syncthreads();                         // RAW
    lds_to_global32(T1, Xs, l, n0, nnodes);
}

// ---------- phase 2: per-edge gather + 64-dot (fp16, fdot2) ----------
__global__ __launch_bounds__(256) void phase2_kernel(
    const int* __restrict__ arcs,
    const u16* __restrict__ T1, const u16* __restrict__ T2,
    const float* __restrict__ bil_b,
    float* __restrict__ out, int E)
{
    const int tid = blockIdx.x * 256 + threadIdx.x;
    const int e = tid >> 3;
    if (e >= E) return;
    const int l8 = tid & 7;

    const int i0 = arcs[2 * e];
    const int i1 = arcs[2 * e + 1];

    const uint4* p1 = (const uint4*)(T1 + (size_t)i0 * HDIM) + l8;
    const uint4* p2 = (const uint4*)(T2 + (size_t)i1 * HDIM) + l8;
    uint4 u = *p1;
    uint4 v = *p2;

    float s = 0.f;
    s = dot2h(u.x, v.x, s);
    s = dot2h(u.y, v.y, s);
    s = dot2h(u.z, v.z, s);
    s = dot2h(u.w, v.w, s);

    s += __shfl_xor(s, 1, 64);
    s += __shfl_xor(s, 2, 64);
    s += __shfl_xor(s, 4, 64);
    if (l8 == 0) out[e] = s + bil_b[0];
}

// ---------- fallback: per-edge full recompute (if ws too small) ----------
__device__ __forceinline__ float lnorm_w(float v, float g, float b) {
    float mu = wave_sum64(v) * 0.015625f;
    float d  = v - mu;
    float var = wave_sum64(d * d) * 0.015625f;
    return d * rsqrtf(var + EPS) * g + b;
}

__global__ __launch_bounds__(256) void edge_direct_kernel(
    const float* __restrict__ z, const int* __restrict__ arcs,
    const float* __restrict__ root_w, const float* __restrict__ root_b,
    const float* __restrict__ lin1_w, const float* __restrict__ lin1_b,
    const float* __restrict__ lin2_w, const float* __restrict__ lin2_b,
    const float* __restrict__ bil_w, const float* __restrict__ bil_b,
    const float* __restrict__ norm_g, const float* __restrict__ norm_b,
    float* __restrict__ out, int E, int nnodes)
{
    __shared__ float W1t[4096], W2t[4096], Bs[4096];
    const int tid = threadIdx.x;
    for (int i = tid; i < 4096; i += 256) {
        int h = i >> 6, k = i & 63;
        W1t[(k << 6) | h] = lin1_w[i];
        W2t[(k << 6) | h] = lin2_w[i];
        Bs[i] = bil_w[i];
    }
    __syncthreads();

    const int lane = tid & 63;
    const float g  = norm_g[lane], bt = norm_b[lane];
    const float b1 = lin1_b[lane], b2 = lin2_b[lane];
    const float rootv = root_w[lane] + root_b[lane];

    const int gwave = (blockIdx.x * 256 + tid) >> 6;
    const int nwaves = (gridDim.x * 256) >> 6;

    for (int e = gwave; e < E; e += nwaves) {
        int i0 = arcs[2 * e], i1 = arcs[2 * e + 1];
        float v0 = (i0 == 0) ? rootv : z[(size_t)(i0 - 1) * HDIM + lane];
        float v1 = (i1 == 0) ? rootv : z[(size_t)(i1 - 1) * HDIM + lane];
        float l0 = lnorm_w(v0, g, bt);
        float l1 = lnorm_w(v1, g, bt);
        float a1 = 0.f, a2 = 0.f;
#pragma unroll
        for (int k = 0; k < 64; ++k) {
            a1 = fmaf(bcast(l0, k), W1t[(k << 6) | lane], a1);
            a2 = fmaf(bcast(l1, k), W2t[(k << 6) | lane], a2);
        }
        float x1 = lnorm_w(fmaxf(a1 + b1, 0.f), g, bt);
        float x2 = lnorm_w(fmaxf(a2 + b2, 0.f), g, bt);
        float w1 = 0.f;
#pragma unroll
        for (int h = 0; h < 64; ++h)
            w1 = fmaf(bcast(x1, h), Bs[(h << 6) | lane], w1);
        float sc = wave_sum64(w1 * x2);
        if (lane == 0) out[e] = sc + bil_b[0];
    }
}

// ---------- launch ----------
extern "C" void kernel_launch(void* const* d_in, const int* in_sizes, int n_in,
                              void* d_out, int out_size, void* d_ws, size_t ws_size,
                              hipStream_t stream) {
    const float* z      = (const float*)d_in[0];
    const int*   arcs   = (const int*)  d_in[1];
    const float* root_w = (const float*)d_in[2];
    const float* root_b = (const float*)d_in[3];
    const float* lin1_w = (const float*)d_in[4];
    const float* lin1_b = (const float*)d_in[5];
    const float* lin2_w = (const float*)d_in[6];
    const float* lin2_b = (const float*)d_in[7];
    const float* bil_w  = (const float*)d_in[8];
    const float* bil_b  = (const float*)d_in[9];
    const float* norm_g = (const float*)d_in[10];
    const float* norm_b = (const float*)d_in[11];
    float* out = (float*)d_out;

    const int E      = in_sizes[1] / 2;
    const int nnodes = in_sizes[0] / HDIM + 1;

    const size_t tbl  = (size_t)nnodes * HDIM * sizeof(u16);
    const size_t need = 2 * tbl + 3 * 4096 * sizeof(u16);

    if (ws_size >= need) {
        u16* T1  = (u16*)d_ws;
        u16* T2  = (u16*)((char*)d_ws + tbl);
        u16* w1h = (u16*)((char*)d_ws + 2 * tbl);
        u16* w2h = w1h + 4096;
        u16* bth = w2h + 4096;

        prep_kernel<<<16, 256, 0, stream>>>(lin1_w, lin2_w, bil_w, w1h, w2h, bth);

        const int blocks1 = (nnodes + 127) / 128;
        phase1_kernel<<<blocks1, 256, 0, stream>>>(
            z, root_w, root_b, w1h, lin1_b, w2h, lin2_b, bth,
            norm_g, norm_b, T1, T2, nnodes);

        const long long thr2 = (long long)E * 8;
        const int blocks2 = (int)((thr2 + 255) / 256);
        phase2_kernel<<<blocks2, 256, 0, stream>>>(arcs, T1, T2, bil_b, out, E);
    } else {
        edge_direct_kernel<<<8192, 256, 0, stream>>>(
            z, arcs, root_w, root_b, lin1_w, lin1_b, lin2_w, lin2_b,
            bil_w, bil_b, norm_g, norm_b, out, E, nnodes);
    }
}